// Round 8
// baseline (198.745 us; speedup 1.0000x reference)
//
#include <hip/hip_runtime.h>
#include <float.h>

// VQ-VAE vector quantizer forward, MI355X — bf16 MFMA with exact 3-way split.
// x: [B=32, C=64, H=64, W=64] fp32; emb: [K=512, D=64] fp32.
// out flat (b, h*w, c): out[g*64 + c] = emb[argmin_k ||x_g - emb_k||^2][c].
//
// R15: DIAGNOSTIC ROUND (pre-committed in R14: dur>=52us -> ablate).
// R9-R14 all land 54-61us / MfmaUtil 33-41% regardless of B-path, barriers,
// prefetch, occupancy, shape. Cycle model can't explain the ~2x gap between
// matrix-pipe demand (~3725 cy/SIMD/round) and measured (~8100). The decider:
// can the MFMA pipe saturate at 4 waves/SIMD with our 2-chain clusters?
// vq_diag_mfma = same prologue/occupancy/cluster structure, register-only B,
// no LDS / barriers / TAIL, x3 tile loop (2304 MFMA/wave) -> strictly the
// slowest dispatch, owns all top-5 rocprof rows.
//   Case A: diag ~74-85us, MfmaUtil>=75%  -> pipe saturable, overhead-bound.
//   Case B: diag ~125-160us, MfmaUtil 40-55% -> chain-structure-bound.
// Real R14 kernel runs unchanged (correct output; 54us, bench 119.78 banked).
//
// Verified layouts (m89/m91/m120): A[m=lane&15][k=quad*8+j],
// B[n=lane&15][k=quad*8+j], D col=lane&15, row=quad*4+reg.

typedef __attribute__((ext_vector_type(8))) short  short8;
typedef __attribute__((ext_vector_type(4))) float  floatx4;

#define HWD 4096
#define CD  64
#define KD  512
#define PT  128    // positions per block
#define KT  128    // fallback path: emb rows per nt
#define ESR 72     // fallback LDS row stride

// ws layout: bs = 32 kt-tiles x 3072 ushorts ([lvl][ch][lane][8], 16 codes
// per tile) = 196608 B; esq = 512 pre-summed |e|^2 floats at 196608;
// diag scratch = 256 floats at 198656 (racing keepalive writes).
#define KT_USH    3072
#define TILE_B    (KT_USH * 2)                            // 6144 B per tile
#define BS_BYTES  (32 * TILE_B)                           // 196608
#define ESQ_OFF   BS_BYTES
#define WS_NEEDED (ESQ_OFF + 512 * (int)sizeof(float))    // 198656
#define SCRATCH_OFF WS_NEEDED
#define WS_DIAG   (SCRATCH_OFF + 1024)                    // 199680

// round-to-nearest-even fp32 -> bf16 (bit-level; inputs are finite)
__device__ inline unsigned short bf16_rne(float v) {
    unsigned int u = __builtin_bit_cast(unsigned int, v);
    u += 0x7fffu + ((u >> 16) & 1u);
    return (unsigned short)(u >> 16);
}
__device__ inline float bf16_val(unsigned short h) {
    return __builtin_bit_cast(float, (unsigned int)h << 16);
}
// exact 3-way split: v = h + m + l + eps, |eps| <= 2^-27 |v|
__device__ inline void split3(float v, unsigned short& h, unsigned short& m,
                              unsigned short& l) {
    h = bf16_rne(v);
    float r1 = v - bf16_val(h);     // exact in fp32
    m = bf16_rne(r1);
    float r2 = r1 - bf16_val(m);    // exact in fp32
    l = bf16_rne(r2);
}

#define MFMA(A, B, C) __builtin_amdgcn_mfma_f32_16x16x32_bf16((A), (B), (C), 0, 0, 0)

// async global -> LDS, 16 B per lane; LDS dest = wave-uniform base + lane*16
__device__ inline void gload_lds16(const void* g, void* l) {
    __builtin_amdgcn_global_load_lds(
        (const __attribute__((address_space(1))) void*)g,
        (__attribute__((address_space(3))) void*)l, 16, 0, 0);
}

// 6-class small->large accumulation, 2 chains (mt). Order identical to
// R12/R14 (bit-identical results). F0,F1=e_h F2,F3=e_m F4,F5=e_l (ch 0/1).
#define CLUSTER6(F0, F1, F2, F3, F4, F5, ACC)                                 \
    { _Pragma("unroll")                                                       \
      for (int mt = 0; mt < 2; ++mt) ACC[mt] = MFMA(al[mt][0], F0, ACC[mt]);  \
      _Pragma("unroll")                                                       \
      for (int mt = 0; mt < 2; ++mt) ACC[mt] = MFMA(al[mt][1], F1, ACC[mt]);  \
      _Pragma("unroll")                                                       \
      for (int mt = 0; mt < 2; ++mt) ACC[mt] = MFMA(am[mt][0], F2, ACC[mt]);  \
      _Pragma("unroll")                                                       \
      for (int mt = 0; mt < 2; ++mt) ACC[mt] = MFMA(am[mt][1], F3, ACC[mt]);  \
      _Pragma("unroll")                                                       \
      for (int mt = 0; mt < 2; ++mt) ACC[mt] = MFMA(ah[mt][0], F4, ACC[mt]);  \
      _Pragma("unroll")                                                       \
      for (int mt = 0; mt < 2; ++mt) ACC[mt] = MFMA(ah[mt][1], F5, ACC[mt]);  \
      _Pragma("unroll")                                                       \
      for (int mt = 0; mt < 2; ++mt) ACC[mt] = MFMA(am[mt][0], F0, ACC[mt]);  \
      _Pragma("unroll")                                                       \
      for (int mt = 0; mt < 2; ++mt) ACC[mt] = MFMA(am[mt][1], F1, ACC[mt]);  \
      _Pragma("unroll")                                                       \
      for (int mt = 0; mt < 2; ++mt) ACC[mt] = MFMA(ah[mt][0], F2, ACC[mt]);  \
      _Pragma("unroll")                                                       \
      for (int mt = 0; mt < 2; ++mt) ACC[mt] = MFMA(ah[mt][1], F3, ACC[mt]);  \
      _Pragma("unroll")                                                       \
      for (int mt = 0; mt < 2; ++mt) ACC[mt] = MFMA(ah[mt][0], F0, ACC[mt]);  \
      _Pragma("unroll")                                                       \
      for (int mt = 0; mt < 2; ++mt) ACC[mt] = MFMA(ah[mt][1], F1, ACC[mt]); }
#define CLUSTER(F, ACC) CLUSTER6(F[0], F[1], F[2], F[3], F[4], F[5], ACC)

// distances + running argmin (k ascending: strict < keeps lowest k)
#define TAIL(ACC, EQ, KV)                                                     \
    { _Pragma("unroll")                                                       \
      for (int mt = 0; mt < 2; ++mt)                                          \
          _Pragma("unroll")                                                   \
          for (int r2 = 0; r2 < 4; ++r2) {                                    \
              float d = fmaf(-2.f, ACC[mt][r2], (EQ));                        \
              int idx = mt * 4 + r2;                                          \
              if (d < bestd[idx]) { bestd[idx] = d; bestk[idx] = (KV); }      \
          } }

// ---- prep: split emb into B-fragment layout + pre-summed |e|^2 ----
__global__ void vq_prep(const float* __restrict__ emb,
                        unsigned short* __restrict__ bs,
                        float* __restrict__ esq) {
    const int t    = blockIdx.x * blockDim.x + threadIdx.x;  // 0..1023
    const int k    = t >> 1;
    const int half = t & 1;
    const int n16  = k & 15;
    const float* eg = emb + (size_t)k * CD + half * 32;
    unsigned short* bb = bs + (size_t)(k >> 4) * KT_USH + half * 512 + n16 * 8;
    float s = 0.f;
    #pragma unroll
    for (int q = 0; q < 8; ++q) {
        float4 ev = *(const float4*)(eg + q * 4);
        float vv[4] = {ev.x, ev.y, ev.z, ev.w};
        #pragma unroll
        for (int i = 0; i < 4; ++i) {
            s = fmaf(vv[i], vv[i], s);
            unsigned short h, m, l;
            split3(vv[i], h, m, l);
            const int c    = half * 32 + q * 4 + i;   // 0..63
            const int quad = (c >> 3) & 3;
            const int j    = c & 7;
            const int off  = quad * 128 + j;          // (quad*16)*8 + j
            bb[off]        = h;                       // lvl 0 (frag lvl*2+ch)
            bb[1024 + off] = m;                       // lvl 1
            bb[2048 + off] = l;                       // lvl 2
        }
    }
    float o = __shfl_xor(s, 1, 64);
    if (half == 0) esq[k] = s + o;    // == R7's esq_p[2k] + esq_p[2k+1]
}

// ---- main kernel: R14 verbatim (4-slot ring, frag prefetch, deferred tail) ----
__launch_bounds__(256, 4)
__global__ void vq_mfma_kernel(const float* __restrict__ x,
                               const unsigned short* __restrict__ bs,
                               const float* __restrict__ esq,
                               const float* __restrict__ emb,
                               float* __restrict__ out) {
    const int tid  = threadIdx.x;
    const int lane = tid & 63;
    const int wv   = __builtin_amdgcn_readfirstlane(tid >> 6);  // 0..3
    const int n16  = lane & 15;   // m for A, n for B, col for D
    const int quad = lane >> 4;   // k-quad for A/B, row-quad for D

    const int g0 = blockIdx.x << 7;   // 128 positions per block
    const int b  = g0 >> 12;          // 128 | 4096: no b straddle
    const int n0 = g0 & 4095;

    __shared__ unsigned short lds_b[4][KT_USH];   // 4 slots x 6144 B (ring)
    __shared__ int bk_s[PT];

    const char* bsb = (const char*)bs;
    char* lds0 = (char*)&lds_b[0][0];

    int st_t[3], st_c[3];
    #pragma unroll
    for (int s = 0; s < 3; ++s) {
        int cidx = wv + 4 * s;          // 0..11
        st_t[s] = (cidx < 6) ? 0 : 1;
        st_c[s] = (cidx < 6) ? cidx : cidx - 6;
    }

    #pragma unroll
    for (int s = 0; s < 3; ++s)
        gload_lds16(bsb + (size_t)st_t[s] * TILE_B + st_c[s] * 1024 + lane * 16,
                    lds0 + st_t[s] * TILE_B + st_c[s] * 1024);

    short8 ah[2][2], am[2][2], al[2][2];
    {
        const float* xb = x + (size_t)b * (CD * HWD) + n0 + wv * 32 + n16;
        #pragma unroll
        for (int mt = 0; mt < 2; ++mt)
            #pragma unroll
            for (int ch = 0; ch < 2; ++ch) {
                #pragma unroll
                for (int j = 0; j < 8; ++j) {
                    float v = xb[(size_t)(ch * 32 + quad * 8 + j) * HWD + mt * 16];
                    unsigned short h, m, l;
                    split3(v, h, m, l);
                    ah[mt][ch][j] = (short)h;
                    am[mt][ch][j] = (short)m;
                    al[mt][ch][j] = (short)l;
                }
            }
    }

    float bestd[8]; int bestk[8];
    #pragma unroll
    for (int i = 0; i < 8; ++i) { bestd[i] = FLT_MAX; bestk[i] = 0; }

    __syncthreads();   // tiles 0,1 resident

    short8 f[6], g[6];
    floatx4 accA[2], accB[2];
    float eqBprev = 0.f;

    #pragma unroll 1
    for (int r = 0; r < 16; ++r) {
        const int tA = 2 * r, tB = 2 * r + 1;

        {
            const char* sb = lds0 + (tA & 3) * TILE_B;
            #pragma unroll
            for (int i = 0; i < 6; ++i)
                f[i] = *(const short8*)(sb + i * 1024 + lane * 16);
        }
        if (r < 15) {
            #pragma unroll
            for (int s = 0; s < 3; ++s) {
                const int tt = tA + 2 + st_t[s];
                gload_lds16(bsb + (size_t)tt * TILE_B + st_c[s] * 1024 + lane * 16,
                            lds0 + (tt & 3) * TILE_B + st_c[s] * 1024);
            }
        }
        const float eqa = esq[tA * 16 + n16];
        const float eqb = esq[tB * 16 + n16];
        {
            const char* sb = lds0 + (tB & 3) * TILE_B;
            #pragma unroll
            for (int i = 0; i < 6; ++i)
                g[i] = *(const short8*)(sb + i * 1024 + lane * 16);
        }
        #pragma unroll
        for (int mt = 0; mt < 2; ++mt) accA[mt] = (floatx4){0.f, 0.f, 0.f, 0.f};
        CLUSTER(f, accA)
        if (r > 0) TAIL(accB, eqBprev, (tA - 1) * 16 + n16)
        #pragma unroll
        for (int mt = 0; mt < 2; ++mt) accB[mt] = (floatx4){0.f, 0.f, 0.f, 0.f};
        CLUSTER(g, accB)
        TAIL(accA, eqa, tA * 16 + n16)
        eqBprev = eqb;
        __syncthreads();
    }
    TAIL(accB, eqBprev, 31 * 16 + n16)

    #pragma unroll
    for (int msk = 1; msk <= 8; msk <<= 1)
        #pragma unroll
        for (int i = 0; i < 8; ++i) {
            float od = __shfl_xor(bestd[i], msk, 64);
            int   ok = __shfl_xor(bestk[i], msk, 64);
            bool take = (od < bestd[i]) || (od == bestd[i] && ok < bestk[i]);
            if (take) { bestd[i] = od; bestk[i] = ok; }
        }
    if (n16 == 0) {
        #pragma unroll
        for (int mt = 0; mt < 2; ++mt)
            #pragma unroll
            for (int r = 0; r < 4; ++r)
                bk_s[wv * 32 + mt * 16 + quad * 4 + r] = bestk[mt * 4 + r];
    }
    __syncthreads();

    const size_t ob = (size_t)g0 * CD;
    for (int it = 0; it < 8; ++it) {
        float v[4]; int pp[4];
        #pragma unroll
        for (int j = 0; j < 4; ++j) {
            int p = (it * 4 + j) * 4 + wv;
            pp[j] = p;
            v[j]  = emb[bk_s[p] * CD + lane];   // L2-hot fp32 row
        }
        #pragma unroll
        for (int j = 0; j < 4; ++j)
            out[ob + (size_t)pp[j] * CD + lane] = v[j];
    }
}

// ---- DIAGNOSTIC: pure-MFMA floor at identical occupancy/chain structure ----
// Register-only B operands, no LDS, no barriers, no TAIL. 48 rounds x 2
// clusters = 2304 MFMA/wave (3x the real kernel) -> strictly the slowest
// dispatch; owns the top-5 rocprof rows. Racing scratch store = keepalive.
__launch_bounds__(256, 4)
__global__ void vq_diag_mfma(const float* __restrict__ x,
                             float* __restrict__ scratch) {
    const int tid  = threadIdx.x;
    const int lane = tid & 63;
    const int wv   = __builtin_amdgcn_readfirstlane(tid >> 6);
    const int n16  = lane & 15;
    const int quad = lane >> 4;
    const int g0 = blockIdx.x << 7;
    const int b  = g0 >> 12;
    const int n0 = g0 & 4095;

    short8 ah[2][2], am[2][2], al[2][2];
    {
        const float* xb = x + (size_t)b * (CD * HWD) + n0 + wv * 32 + n16;
        #pragma unroll
        for (int mt = 0; mt < 2; ++mt)
            #pragma unroll
            for (int ch = 0; ch < 2; ++ch) {
                #pragma unroll
                for (int j = 0; j < 8; ++j) {
                    float v = xb[(size_t)(ch * 32 + quad * 8 + j) * HWD + mt * 16];
                    unsigned short h, m, l;
                    split3(v, h, m, l);
                    ah[mt][ch][j] = (short)h;
                    am[mt][ch][j] = (short)m;
                    al[mt][ch][j] = (short)l;
                }
            }
    }

    floatx4 accA[2], accB[2];
    #pragma unroll
    for (int mt = 0; mt < 2; ++mt) {
        accA[mt] = (floatx4){0.f, 0.f, 0.f, 0.f};
        accB[mt] = (floatx4){0.f, 0.f, 0.f, 0.f};
    }

    #pragma unroll 1
    for (int r = 0; r < 48; ++r) {
        CLUSTER6(ah[0][0], ah[0][1], ah[1][0], ah[1][1], am[0][0], am[0][1], accA)
        CLUSTER6(al[0][0], al[0][1], al[1][0], al[1][1], am[1][0], am[1][1], accB)
    }

    float s = accA[0][0] + accA[1][1] + accB[0][2] + accB[1][3];
    scratch[tid] = s;   // racing across blocks: keepalive only
}

// ---- fallback (no workspace): verbatim R7 kernel, 123.7 us known-good ----
__launch_bounds__(256, 2)
__global__ void vq_mfma_fb(const float* __restrict__ x,
                           const float* __restrict__ emb,
                           float* __restrict__ out) {
    const int tid  = threadIdx.x;
    const int lane = tid & 63;
    const int wv   = __builtin_amdgcn_readfirstlane(tid >> 6);  // 0..3
    const int n16  = lane & 15;
    const int quad = lane >> 4;

    const int g0 = blockIdx.x << 8;
    const int b  = g0 >> 12;
    const int n0 = g0 & 4095;

    __shared__ unsigned short es_h[KT][ESR];
    __shared__ unsigned short es_m[KT][ESR];
    __shared__ unsigned short es_l[KT][ESR];
    __shared__ float esq_p[2 * KT];
    __shared__ int   bk_s[256];

    short8 ah[4][2], am[4][2], al[4][2];
    {
        const float* xb = x + (size_t)b * (CD * HWD) + n0 + wv * 64 + n16;
        #pragma unroll
        for (int mt = 0; mt < 4; ++mt)
            #pragma unroll
            for (int ch = 0; ch < 2; ++ch) {
                #pragma unroll
                for (int j = 0; j < 8; ++j) {
                    float v = xb[(size_t)(ch * 32 + quad * 8 + j) * HWD + mt * 16];
                    unsigned short h, m, l;
                    split3(v, h, m, l);
                    ah[mt][ch][j] = (short)h;
                    am[mt][ch][j] = (short)m;
                    al[mt][ch][j] = (short)l;
                }
            }
    }

    float bestd[16]; int bestk[16];
    #pragma unroll
    for (int i = 0; i < 16; ++i) { bestd[i] = FLT_MAX; bestk[i] = 0; }

    const int lr   = tid >> 1;
    const int half = tid & 1;

    for (int nt = 0; nt < KD / KT; ++nt) {
        __syncthreads();
        {
            const float* eg = emb + (size_t)(nt * KT + lr) * CD + half * 32;
            float s = 0.f;
            #pragma unroll
            for (int q = 0; q < 8; ++q) {
                float4 ev = *(const float4*)(eg + q * 4);
                float vv[4] = {ev.x, ev.y, ev.z, ev.w};
                ushort4 h4, m4, l4;
                unsigned short* hp = (unsigned short*)&h4;
                unsigned short* mp = (unsigned short*)&m4;
                unsigned short* lp = (unsigned short*)&l4;
                #pragma unroll
                for (int i = 0; i < 4; ++i) {
                    s = fmaf(vv[i], vv[i], s);
                    split3(vv[i], hp[i], mp[i], lp[i]);
                }
                int c0 = half * 32 + q * 4;
                *(ushort4*)&es_h[lr][c0] = h4;
                *(ushort4*)&es_m[lr][c0] = m4;
                *(ushort4*)&es_l[lr][c0] = l4;
            }
            esq_p[2 * lr + half] = s;
        }
        __syncthreads();

        #pragma unroll 2
        for (int ln = 0; ln < 8; ++ln) {
            const int krow = ln * 16 + n16;
            const unsigned short* ph = &es_h[krow][quad * 8];
            const unsigned short* pm = &es_m[krow][quad * 8];
            const unsigned short* pl = &es_l[krow][quad * 8];
            short8 bh0 = *(const short8*)ph,  bh1 = *(const short8*)(ph + 32);
            short8 bm0 = *(const short8*)pm,  bm1 = *(const short8*)(pm + 32);
            short8 bl0 = *(const short8*)pl,  bl1 = *(const short8*)(pl + 32);
            const float eq = esq_p[2 * krow] + esq_p[2 * krow + 1];
            const int   kv = nt * KT + ln * 16 + n16;

            floatx4 acc[4];
            #pragma unroll
            for (int mt = 0; mt < 4; ++mt) acc[mt] = (floatx4){0.f, 0.f, 0.f, 0.f};

            #define STEPF(AR, B0, B1)                                         \
                { _Pragma("unroll")                                           \
                  for (int mt = 0; mt < 4; ++mt) acc[mt] = MFMA(AR[mt][0], B0, acc[mt]); \
                  _Pragma("unroll")                                           \
                  for (int mt = 0; mt < 4; ++mt) acc[mt] = MFMA(AR[mt][1], B1, acc[mt]); }
            STEPF(al, bh0, bh1)
            STEPF(am, bm0, bm1)
            STEPF(ah, bl0, bl1)
            STEPF(am, bh0, bh1)
            STEPF(ah, bm0, bm1)
            STEPF(ah, bh0, bh1)
            #undef STEPF

            #pragma unroll
            for (int mt = 0; mt < 4; ++mt)
                #pragma unroll
                for (int r = 0; r < 4; ++r) {
                    float d = fmaf(-2.f, acc[mt][r], eq);
                    int idx = mt * 4 + r;
                    if (d < bestd[idx]) { bestd[idx] = d; bestk[idx] = kv; }
                }
        }
    }

    #pragma unroll
    for (int msk = 1; msk <= 8; msk <<= 1)
        #pragma unroll
        for (int i = 0; i < 16; ++i) {
            float od = __shfl_xor(bestd[i], msk, 64);
            int   ok = __shfl_xor(bestk[i], msk, 64);
            bool take = (od < bestd[i]) || (od == bestd[i] && ok < bestk[i]);
            if (take) { bestd[i] = od; bestk[i] = ok; }
        }
    if (n16 == 0) {
        #pragma unroll
        for (int mt = 0; mt < 4; ++mt)
            #pragma unroll
            for (int r = 0; r < 4; ++r)
                bk_s[wv * 64 + mt * 16 + quad * 4 + r] = bestk[mt * 4 + r];
    }
    __syncthreads();

    const size_t ob = (size_t)g0 * CD;
    for (int it = 0; it < 16; ++it) {
        float v[4]; int pp[4];
        #pragma unroll
        for (int j = 0; j < 4; ++j) {
            int p = (it * 4 + j) * 4 + wv;
            pp[j] = p;
            v[j]  = emb[bk_s[p] * CD + lane];
        }
        #pragma unroll
        for (int j = 0; j < 4; ++j)
            out[ob + (size_t)pp[j] * CD + lane] = v[j];
    }
}

extern "C" void kernel_launch(void* const* d_in, const int* in_sizes, int n_in,
                              void* d_out, int out_size, void* d_ws, size_t ws_size,
                              hipStream_t stream) {
    const float* x   = (const float*)d_in[0];   // 32*64*64*64
    const float* emb = (const float*)d_in[1];   // 512*64
    float* out = (float*)d_out;                 // 8388608 floats

    if (d_ws != nullptr && ws_size >= (size_t)WS_NEEDED) {
        unsigned short* bs = (unsigned short*)d_ws;     // 196608 B
        float* esq = (float*)((char*)d_ws + ESQ_OFF);   // 512 floats
        vq_prep<<<16, 64, 0, stream>>>(emb, bs, esq);
        vq_mfma_kernel<<<1024, 256, 0, stream>>>(x, bs, esq, emb, out);
        if (ws_size >= (size_t)WS_DIAG) {
            float* scratch = (float*)((char*)d_ws + SCRATCH_OFF);
            vq_diag_mfma<<<1024, 256, 0, stream>>>(x, scratch);
        }
    } else {
        vq_mfma_fb<<<512, 256, 0, stream>>>(x, emb, out);
    }
}

// Round 9
// 178.598 us; speedup vs baseline: 1.1128x; 1.1128x over previous
//
#include <hip/hip_runtime.h>
#include <float.h>

// VQ-VAE vector quantizer forward, MI355X — bf16 MFMA with exact 3-way split.
// x: [B=32, C=64, H=64, W=64] fp32; emb: [K=512, D=64] fp32.
// out flat (b, h*w, c): out[g*64 + c] = emb[argmin_k ||x_g - emb_k||^2][c].
//
// R16 = R14 + setprio + esq-in-LDS. R15 diag measured the pure-MFMA wall at
// this occupancy/chain structure: 30.5us (76% MfmaUtil, 23.8cy/MFMA/SIMD).
// R14's 54us = wall + ~23.5us of phase overhead: barrier-synced rounds align
// the TAIL-VALU bursts (~920cy/SIMD), ds_read bursts (~576cy) and lgkm waits
// so they ADD to the 4570cy MFMA phase instead of overlapping (7500cy/round
// measured). R10 showed the no-barrier alternative is L2-BW-bound (57 B/cy
// demand vs ~56 ceiling) — so keep LDS staging, break the role-lock instead:
// s_setprio(1) around each 24-MFMA cluster (T5; m218b regime: +21-25% on
// barrier-phase-split schedules). esq reads move to LDS (staged once, 2KB)
// to kill the per-round L2 scalar loads. Numerics bit-identical to R7-R14.
// Pre-committed: dur>=52us -> T5 exhausted, structure ceiling ~54us declared.
//
// Verified layouts (m89/m91/m120): A[m=lane&15][k=quad*8+j],
// B[n=lane&15][k=quad*8+j], D col=lane&15, row=quad*4+reg.

typedef __attribute__((ext_vector_type(8))) short  short8;
typedef __attribute__((ext_vector_type(4))) float  floatx4;

#define HWD 4096
#define CD  64
#define KD  512
#define PT  128    // positions per block
#define KT  128    // fallback path: emb rows per nt
#define ESR 72     // fallback LDS row stride

// ws layout: bs = 32 kt-tiles x 3072 ushorts ([lvl][ch][lane][8], 16 codes
// per tile) = 196608 B; esq = 512 pre-summed |e|^2 floats at 196608.
#define KT_USH    3072
#define TILE_B    (KT_USH * 2)                            // 6144 B per tile
#define BS_BYTES  (32 * TILE_B)                           // 196608
#define ESQ_OFF   BS_BYTES
#define WS_NEEDED (ESQ_OFF + 512 * (int)sizeof(float))    // 198656

// round-to-nearest-even fp32 -> bf16 (bit-level; inputs are finite)
__device__ inline unsigned short bf16_rne(float v) {
    unsigned int u = __builtin_bit_cast(unsigned int, v);
    u += 0x7fffu + ((u >> 16) & 1u);
    return (unsigned short)(u >> 16);
}
__device__ inline float bf16_val(unsigned short h) {
    return __builtin_bit_cast(float, (unsigned int)h << 16);
}
// exact 3-way split: v = h + m + l + eps, |eps| <= 2^-27 |v|
__device__ inline void split3(float v, unsigned short& h, unsigned short& m,
                              unsigned short& l) {
    h = bf16_rne(v);
    float r1 = v - bf16_val(h);     // exact in fp32
    m = bf16_rne(r1);
    float r2 = r1 - bf16_val(m);    // exact in fp32
    l = bf16_rne(r2);
}

#define MFMA(A, B, C) __builtin_amdgcn_mfma_f32_16x16x32_bf16((A), (B), (C), 0, 0, 0)

// async global -> LDS, 16 B per lane; LDS dest = wave-uniform base + lane*16
__device__ inline void gload_lds16(const void* g, void* l) {
    __builtin_amdgcn_global_load_lds(
        (const __attribute__((address_space(1))) void*)g,
        (__attribute__((address_space(3))) void*)l, 16, 0, 0);
}

// 6-class small->large accumulation, 2 chains (mt). Order identical to
// R12/R14 (bit-identical results). F[0],F[1]=e_h F[2],F[3]=e_m F[4],F[5]=e_l.
#define CLUSTER(F, ACC)                                                       \
    { _Pragma("unroll")                                                       \
      for (int mt = 0; mt < 2; ++mt) ACC[mt] = MFMA(al[mt][0], F[0], ACC[mt]); \
      _Pragma("unroll")                                                       \
      for (int mt = 0; mt < 2; ++mt) ACC[mt] = MFMA(al[mt][1], F[1], ACC[mt]); \
      _Pragma("unroll")                                                       \
      for (int mt = 0; mt < 2; ++mt) ACC[mt] = MFMA(am[mt][0], F[2], ACC[mt]); \
      _Pragma("unroll")                                                       \
      for (int mt = 0; mt < 2; ++mt) ACC[mt] = MFMA(am[mt][1], F[3], ACC[mt]); \
      _Pragma("unroll")                                                       \
      for (int mt = 0; mt < 2; ++mt) ACC[mt] = MFMA(ah[mt][0], F[4], ACC[mt]); \
      _Pragma("unroll")                                                       \
      for (int mt = 0; mt < 2; ++mt) ACC[mt] = MFMA(ah[mt][1], F[5], ACC[mt]); \
      _Pragma("unroll")                                                       \
      for (int mt = 0; mt < 2; ++mt) ACC[mt] = MFMA(am[mt][0], F[0], ACC[mt]); \
      _Pragma("unroll")                                                       \
      for (int mt = 0; mt < 2; ++mt) ACC[mt] = MFMA(am[mt][1], F[1], ACC[mt]); \
      _Pragma("unroll")                                                       \
      for (int mt = 0; mt < 2; ++mt) ACC[mt] = MFMA(ah[mt][0], F[2], ACC[mt]); \
      _Pragma("unroll")                                                       \
      for (int mt = 0; mt < 2; ++mt) ACC[mt] = MFMA(ah[mt][1], F[3], ACC[mt]); \
      _Pragma("unroll")                                                       \
      for (int mt = 0; mt < 2; ++mt) ACC[mt] = MFMA(ah[mt][0], F[0], ACC[mt]); \
      _Pragma("unroll")                                                       \
      for (int mt = 0; mt < 2; ++mt) ACC[mt] = MFMA(ah[mt][1], F[1], ACC[mt]); }

// distances + running argmin (k ascending: strict < keeps lowest k)
#define TAIL(ACC, EQ, KV)                                                     \
    { _Pragma("unroll")                                                       \
      for (int mt = 0; mt < 2; ++mt)                                          \
          _Pragma("unroll")                                                   \
          for (int r2 = 0; r2 < 4; ++r2) {                                    \
              float d = fmaf(-2.f, ACC[mt][r2], (EQ));                        \
              int idx = mt * 4 + r2;                                          \
              if (d < bestd[idx]) { bestd[idx] = d; bestk[idx] = (KV); }      \
          } }

// ---- prep: split emb into B-fragment layout + pre-summed |e|^2 ----
__global__ void vq_prep(const float* __restrict__ emb,
                        unsigned short* __restrict__ bs,
                        float* __restrict__ esq) {
    const int t    = blockIdx.x * blockDim.x + threadIdx.x;  // 0..1023
    const int k    = t >> 1;
    const int half = t & 1;
    const int n16  = k & 15;
    const float* eg = emb + (size_t)k * CD + half * 32;
    unsigned short* bb = bs + (size_t)(k >> 4) * KT_USH + half * 512 + n16 * 8;
    float s = 0.f;
    #pragma unroll
    for (int q = 0; q < 8; ++q) {
        float4 ev = *(const float4*)(eg + q * 4);
        float vv[4] = {ev.x, ev.y, ev.z, ev.w};
        #pragma unroll
        for (int i = 0; i < 4; ++i) {
            s = fmaf(vv[i], vv[i], s);
            unsigned short h, m, l;
            split3(vv[i], h, m, l);
            const int c    = half * 32 + q * 4 + i;   // 0..63
            const int quad = (c >> 3) & 3;
            const int j    = c & 7;
            const int off  = quad * 128 + j;          // (quad*16)*8 + j
            bb[off]        = h;                       // lvl 0 (frag lvl*2+ch)
            bb[1024 + off] = m;                       // lvl 1
            bb[2048 + off] = l;                       // lvl 2
        }
    }
    float o = __shfl_xor(s, 1, 64);
    if (half == 0) esq[k] = s + o;    // == R7's esq_p[2k] + esq_p[2k+1]
}

// ---- main kernel: 4-slot ring + setprio'd clusters + LDS esq ----
__launch_bounds__(256, 4)
__global__ void vq_mfma_kernel(const float* __restrict__ x,
                               const unsigned short* __restrict__ bs,
                               const float* __restrict__ esq,
                               const float* __restrict__ emb,
                               float* __restrict__ out) {
    const int tid  = threadIdx.x;
    const int lane = tid & 63;
    const int wv   = __builtin_amdgcn_readfirstlane(tid >> 6);  // 0..3
    const int n16  = lane & 15;   // m for A, n for B, col for D
    const int quad = lane >> 4;   // k-quad for A/B, row-quad for D

    const int g0 = blockIdx.x << 7;   // 128 positions per block
    const int b  = g0 >> 12;          // 128 | 4096: no b straddle
    const int n0 = g0 & 4095;

    __shared__ unsigned short lds_b[4][KT_USH];   // 4 slots x 6144 B (ring)
    __shared__ float esq_s[512];                  // 2 KB: |e|^2 per code
    __shared__ int bk_s[PT];

    const char* bsb = (const char*)bs;
    char* lds0 = (char*)&lds_b[0][0];

    int st_t[3], st_c[3];
    #pragma unroll
    for (int s = 0; s < 3; ++s) {
        int cidx = wv + 4 * s;          // 0..11
        st_t[s] = (cidx < 6) ? 0 : 1;
        st_c[s] = (cidx < 6) ? cidx : cidx - 6;
    }

    // ---- stage tiles 0,1 + esq (2 chunks, waves 0-1); DMA latency hides
    //      under the split3 prologue ----
    #pragma unroll
    for (int s = 0; s < 3; ++s)
        gload_lds16(bsb + (size_t)st_t[s] * TILE_B + st_c[s] * 1024 + lane * 16,
                    lds0 + st_t[s] * TILE_B + st_c[s] * 1024);
    if (wv < 2)
        gload_lds16((const char*)esq + wv * 1024 + lane * 16,
                    (char*)esq_s + wv * 1024);

    short8 ah[2][2], am[2][2], al[2][2];
    {
        const float* xb = x + (size_t)b * (CD * HWD) + n0 + wv * 32 + n16;
        #pragma unroll
        for (int mt = 0; mt < 2; ++mt)
            #pragma unroll
            for (int ch = 0; ch < 2; ++ch) {
                #pragma unroll
                for (int j = 0; j < 8; ++j) {
                    float v = xb[(size_t)(ch * 32 + quad * 8 + j) * HWD + mt * 16];
                    unsigned short h, m, l;
                    split3(v, h, m, l);
                    ah[mt][ch][j] = (short)h;
                    am[mt][ch][j] = (short)m;
                    al[mt][ch][j] = (short)l;
                }
            }
    }

    float bestd[8]; int bestk[8];
    #pragma unroll
    for (int i = 0; i < 8; ++i) { bestd[i] = FLT_MAX; bestk[i] = 0; }

    __syncthreads();   // tiles 0,1 + esq resident

    short8 f[6], g[6];
    floatx4 accA[2], accB[2];
    float eqBprev = 0.f;

    #pragma unroll 1
    for (int r = 0; r < 16; ++r) {
        const int tA = 2 * r, tB = 2 * r + 1;

        // (a) f <- frags(tile tA) from slot tA&3 (staged round r-1)
        {
            const char* sb = lds0 + (tA & 3) * TILE_B;
            #pragma unroll
            for (int i = 0; i < 6; ++i)
                f[i] = *(const short8*)(sb + i * 1024 + lane * 16);
        }
        // (b) stage tiles tA+2, tB+2 into the slots read last round
        if (r < 15) {
            #pragma unroll
            for (int s = 0; s < 3; ++s) {
                const int tt = tA + 2 + st_t[s];
                gload_lds16(bsb + (size_t)tt * TILE_B + st_c[s] * 1024 + lane * 16,
                            lds0 + (tt & 3) * TILE_B + st_c[s] * 1024);
            }
        }
        const float eqa = esq_s[tA * 16 + n16];   // ds_read_b32 (LDS-hot)
        const float eqb = esq_s[tB * 16 + n16];
        // (c) g <- frags(tile tB) from slot tB&3 (staged round r-1)
        {
            const char* sb = lds0 + (tB & 3) * TILE_B;
            #pragma unroll
            for (int i = 0; i < 6; ++i)
                g[i] = *(const short8*)(sb + i * 1024 + lane * 16);
        }
        // (d) MFMA on f -> accA  (setprio: MFMA-phase waves preempt)
        #pragma unroll
        for (int mt = 0; mt < 2; ++mt) accA[mt] = (floatx4){0.f, 0.f, 0.f, 0.f};
        __builtin_amdgcn_s_setprio(1);
        CLUSTER(f, accA)
        __builtin_amdgcn_s_setprio(0);
        // (e) deferred argmin for tile 2r-1 (acc done since last round)
        if (r > 0) TAIL(accB, eqBprev, (tA - 1) * 16 + n16)
        // (f) MFMA on g -> accB
        #pragma unroll
        for (int mt = 0; mt < 2; ++mt) accB[mt] = (floatx4){0.f, 0.f, 0.f, 0.f};
        __builtin_amdgcn_s_setprio(1);
        CLUSTER(g, accB)
        __builtin_amdgcn_s_setprio(0);
        // (g) argmin for tile tA (its chain drained under (e)+(f))
        TAIL(accA, eqa, tA * 16 + n16)
        eqBprev = eqb;
        // (h) barrier: drains this round's DMA; protects slot overwrite
        __syncthreads();
    }
    TAIL(accB, eqBprev, 31 * 16 + n16)

    // ---- cross-lane argmin over the 16 code-columns (lane bits 0..3) ----
    #pragma unroll
    for (int msk = 1; msk <= 8; msk <<= 1)
        #pragma unroll
        for (int i = 0; i < 8; ++i) {
            float od = __shfl_xor(bestd[i], msk, 64);
            int   ok = __shfl_xor(bestk[i], msk, 64);
            bool take = (od < bestd[i]) || (od == bestd[i] && ok < bestk[i]);
            if (take) { bestd[i] = od; bestk[i] = ok; }
        }
    // D row = quad*4 + r within tile -> pos = wv*32 + mt*16 + quad*4 + r
    if (n16 == 0) {
        #pragma unroll
        for (int mt = 0; mt < 2; ++mt)
            #pragma unroll
            for (int r = 0; r < 4; ++r)
                bk_s[wv * 32 + mt * 16 + quad * 4 + r] = bestk[mt * 4 + r];
    }
    __syncthreads();

    // ---- gather epilogue: wave-uniform rows, 256-B coalesced, batched ----
    const size_t ob = (size_t)g0 * CD;
    for (int it = 0; it < 8; ++it) {
        float v[4]; int pp[4];
        #pragma unroll
        for (int j = 0; j < 4; ++j) {
            int p = (it * 4 + j) * 4 + wv;
            pp[j] = p;
            v[j]  = emb[bk_s[p] * CD + lane];   // L2-hot fp32 row
        }
        #pragma unroll
        for (int j = 0; j < 4; ++j)
            out[ob + (size_t)pp[j] * CD + lane] = v[j];
    }
}

// ---- fallback (no workspace): verbatim R7 kernel, 123.7 us known-good ----
__launch_bounds__(256, 2)
__global__ void vq_mfma_fb(const float* __restrict__ x,
                           const float* __restrict__ emb,
                           float* __restrict__ out) {
    const int tid  = threadIdx.x;
    const int lane = tid & 63;
    const int wv   = __builtin_amdgcn_readfirstlane(tid >> 6);  // 0..3
    const int n16  = lane & 15;
    const int quad = lane >> 4;

    const int g0 = blockIdx.x << 8;
    const int b  = g0 >> 12;
    const int n0 = g0 & 4095;

    __shared__ unsigned short es_h[KT][ESR];
    __shared__ unsigned short es_m[KT][ESR];
    __shared__ unsigned short es_l[KT][ESR];
    __shared__ float esq_p[2 * KT];
    __shared__ int   bk_s[256];

    short8 ah[4][2], am[4][2], al[4][2];
    {
        const float* xb = x + (size_t)b * (CD * HWD) + n0 + wv * 64 + n16;
        #pragma unroll
        for (int mt = 0; mt < 4; ++mt)
            #pragma unroll
            for (int ch = 0; ch < 2; ++ch) {
                #pragma unroll
                for (int j = 0; j < 8; ++j) {
                    float v = xb[(size_t)(ch * 32 + quad * 8 + j) * HWD + mt * 16];
                    unsigned short h, m, l;
                    split3(v, h, m, l);
                    ah[mt][ch][j] = (short)h;
                    am[mt][ch][j] = (short)m;
                    al[mt][ch][j] = (short)l;
                }
            }
    }

    float bestd[16]; int bestk[16];
    #pragma unroll
    for (int i = 0; i < 16; ++i) { bestd[i] = FLT_MAX; bestk[i] = 0; }

    const int lr   = tid >> 1;
    const int half = tid & 1;

    for (int nt = 0; nt < KD / KT; ++nt) {
        __syncthreads();
        {
            const float* eg = emb + (size_t)(nt * KT + lr) * CD + half * 32;
            float s = 0.f;
            #pragma unroll
            for (int q = 0; q < 8; ++q) {
                float4 ev = *(const float4*)(eg + q * 4);
                float vv[4] = {ev.x, ev.y, ev.z, ev.w};
                ushort4 h4, m4, l4;
                unsigned short* hp = (unsigned short*)&h4;
                unsigned short* mp = (unsigned short*)&m4;
                unsigned short* lp = (unsigned short*)&l4;
                #pragma unroll
                for (int i = 0; i < 4; ++i) {
                    s = fmaf(vv[i], vv[i], s);
                    split3(vv[i], hp[i], mp[i], lp[i]);
                }
                int c0 = half * 32 + q * 4;
                *(ushort4*)&es_h[lr][c0] = h4;
                *(ushort4*)&es_m[lr][c0] = m4;
                *(ushort4*)&es_l[lr][c0] = l4;
            }
            esq_p[2 * lr + half] = s;
        }
        __syncthreads();

        #pragma unroll 2
        for (int ln = 0; ln < 8; ++ln) {
            const int krow = ln * 16 + n16;
            const unsigned short* ph = &es_h[krow][quad * 8];
            const unsigned short* pm = &es_m[krow][quad * 8];
            const unsigned short* pl = &es_l[krow][quad * 8];
            short8 bh0 = *(const short8*)ph,  bh1 = *(const short8*)(ph + 32);
            short8 bm0 = *(const short8*)pm,  bm1 = *(const short8*)(pm + 32);
            short8 bl0 = *(const short8*)pl,  bl1 = *(const short8*)(pl + 32);
            const float eq = esq_p[2 * krow] + esq_p[2 * krow + 1];
            const int   kv = nt * KT + ln * 16 + n16;

            floatx4 acc[4];
            #pragma unroll
            for (int mt = 0; mt < 4; ++mt) acc[mt] = (floatx4){0.f, 0.f, 0.f, 0.f};

            #define STEPF(AR, B0, B1)                                         \
                { _Pragma("unroll")                                           \
                  for (int mt = 0; mt < 4; ++mt) acc[mt] = MFMA(AR[mt][0], B0, acc[mt]); \
                  _Pragma("unroll")                                           \
                  for (int mt = 0; mt < 4; ++mt) acc[mt] = MFMA(AR[mt][1], B1, acc[mt]); }
            STEPF(al, bh0, bh1)
            STEPF(am, bm0, bm1)
            STEPF(ah, bl0, bl1)
            STEPF(am, bh0, bh1)
            STEPF(ah, bm0, bm1)
            STEPF(ah, bh0, bh1)
            #undef STEPF

            #pragma unroll
            for (int mt = 0; mt < 4; ++mt)
                #pragma unroll
                for (int r = 0; r < 4; ++r) {
                    float d = fmaf(-2.f, acc[mt][r], eq);
                    int idx = mt * 4 + r;
                    if (d < bestd[idx]) { bestd[idx] = d; bestk[idx] = kv; }
                }
        }
    }

    #pragma unroll
    for (int msk = 1; msk <= 8; msk <<= 1)
        #pragma unroll
        for (int i = 0; i < 16; ++i) {
            float od = __shfl_xor(bestd[i], msk, 64);
            int   ok = __shfl_xor(bestk[i], msk, 64);
            bool take = (od < bestd[i]) || (od == bestd[i] && ok < bestk[i]);
            if (take) { bestd[i] = od; bestk[i] = ok; }
        }
    if (n16 == 0) {
        #pragma unroll
        for (int mt = 0; mt < 4; ++mt)
            #pragma unroll
            for (int r = 0; r < 4; ++r)
                bk_s[wv * 64 + mt * 16 + quad * 4 + r] = bestk[mt * 4 + r];
    }
    __syncthreads();

    const size_t ob = (size_t)g0 * CD;
    for (int it = 0; it < 16; ++it) {
        float v[4]; int pp[4];
        #pragma unroll
        for (int j = 0; j < 4; ++j) {
            int p = (it * 4 + j) * 4 + wv;
            pp[j] = p;
            v[j]  = emb[bk_s[p] * CD + lane];
        }
        #pragma unroll
        for (int j = 0; j < 4; ++j)
            out[ob + (size_t)pp[j] * CD + lane] = v[j];
    }
}

extern "C" void kernel_launch(void* const* d_in, const int* in_sizes, int n_in,
                              void* d_out, int out_size, void* d_ws, size_t ws_size,
                              hipStream_t stream) {
    const float* x   = (const float*)d_in[0];   // 32*64*64*64
    const float* emb = (const float*)d_in[1];   // 512*64
    float* out = (float*)d_out;                 // 8388608 floats

    if (d_ws != nullptr && ws_size >= (size_t)WS_NEEDED) {
        unsigned short* bs = (unsigned short*)d_ws;     // 196608 B
        float* esq = (float*)((char*)d_ws + ESQ_OFF);   // 512 floats
        vq_prep<<<16, 64, 0, stream>>>(emb, bs, esq);
        vq_mfma_kernel<<<1024, 256, 0, stream>>>(x, bs, esq, emb, out);
    } else {
        vq_mfma_fb<<<512, 256, 0, stream>>>(x, emb, out);
    }
}

// Round 10
// 122.676 us; speedup vs baseline: 1.6201x; 1.4559x over previous
//
#include <hip/hip_runtime.h>
#include <float.h>

// VQ-VAE vector quantizer forward, MI355X — bf16 MFMA with exact 3-way split.
// x: [B=32, C=64, H=64, W=64] fp32; emb: [K=512, D=64] fp32.
// out flat (b, h*w, c): out[g*64 + c] = emb[argmin_k ||x_g - emb_k||^2][c].
//
// R17 = R14 verbatim (revert of R16). R16's setprio pinned the scheduler,
// extended live ranges (f[6]+g[6]+accs+A-frags), blew the 128-VGPR cap at
// launch_bounds(256,4) and spilled (~23.5MB extra WRITE, ~12MB extra FETCH,
// MfmaUtil 18%, 113.9us). R14 is the session best: dispatch 54.0-56.4us,
// bench 119.78us, MfmaUtil ~40%.
// Structure: prep kernel pre-splits emb into per-lane MFMA B-fragment layout
// (192KB ws, L2-resident) + pre-summed |e|^2; main kernel = 4-slot LDS ring
// (24KB), global_load_lds staging, frag prefetch before each MFMA cluster,
// deferred argmin TAIL, 16 barriers. 4 blocks/CU. Numerics bit-identical to
// the R7 baseline (same split3, same 6-class small->large order, same fmaf
// chains, same k-ascending strict-< argmin).
// Measured walls (R15 diag): pure-MFMA at this chain structure = 30.5us
// (76% MfmaUtil); ideal MFMA floor 24.8us. R9-R16 scheduling variants all
// land 54-61us -> the ~23us phase overhead resists HIP-source scheduling.
//
// Verified layouts (m89/m91/m120): A[m=lane&15][k=quad*8+j],
// B[n=lane&15][k=quad*8+j], D col=lane&15, row=quad*4+reg.

typedef __attribute__((ext_vector_type(8))) short  short8;
typedef __attribute__((ext_vector_type(4))) float  floatx4;

#define HWD 4096
#define CD  64
#define KD  512
#define PT  128    // positions per block
#define KT  128    // fallback path: emb rows per nt
#define ESR 72     // fallback LDS row stride

// ws layout: bs = 32 kt-tiles x 3072 ushorts ([lvl][ch][lane][8], 16 codes
// per tile) = 196608 B; esq = 512 pre-summed |e|^2 floats at 196608.
#define KT_USH    3072
#define TILE_B    (KT_USH * 2)                            // 6144 B per tile
#define BS_BYTES  (32 * TILE_B)                           // 196608
#define ESQ_OFF   BS_BYTES
#define WS_NEEDED (ESQ_OFF + 512 * (int)sizeof(float))    // 198656

// round-to-nearest-even fp32 -> bf16 (bit-level; inputs are finite)
__device__ inline unsigned short bf16_rne(float v) {
    unsigned int u = __builtin_bit_cast(unsigned int, v);
    u += 0x7fffu + ((u >> 16) & 1u);
    return (unsigned short)(u >> 16);
}
__device__ inline float bf16_val(unsigned short h) {
    return __builtin_bit_cast(float, (unsigned int)h << 16);
}
// exact 3-way split: v = h + m + l + eps, |eps| <= 2^-27 |v|
__device__ inline void split3(float v, unsigned short& h, unsigned short& m,
                              unsigned short& l) {
    h = bf16_rne(v);
    float r1 = v - bf16_val(h);     // exact in fp32
    m = bf16_rne(r1);
    float r2 = r1 - bf16_val(m);    // exact in fp32
    l = bf16_rne(r2);
}

#define MFMA(A, B, C) __builtin_amdgcn_mfma_f32_16x16x32_bf16((A), (B), (C), 0, 0, 0)

// async global -> LDS, 16 B per lane; LDS dest = wave-uniform base + lane*16
__device__ inline void gload_lds16(const void* g, void* l) {
    __builtin_amdgcn_global_load_lds(
        (const __attribute__((address_space(1))) void*)g,
        (__attribute__((address_space(3))) void*)l, 16, 0, 0);
}

// 6-class small->large accumulation, 2 chains (mt). Order identical to
// R12 (bit-identical results). F[0],F[1]=e_h F[2],F[3]=e_m F[4],F[5]=e_l.
#define CLUSTER(F, ACC)                                                       \
    { _Pragma("unroll")                                                       \
      for (int mt = 0; mt < 2; ++mt) ACC[mt] = MFMA(al[mt][0], F[0], ACC[mt]); \
      _Pragma("unroll")                                                       \
      for (int mt = 0; mt < 2; ++mt) ACC[mt] = MFMA(al[mt][1], F[1], ACC[mt]); \
      _Pragma("unroll")                                                       \
      for (int mt = 0; mt < 2; ++mt) ACC[mt] = MFMA(am[mt][0], F[2], ACC[mt]); \
      _Pragma("unroll")                                                       \
      for (int mt = 0; mt < 2; ++mt) ACC[mt] = MFMA(am[mt][1], F[3], ACC[mt]); \
      _Pragma("unroll")                                                       \
      for (int mt = 0; mt < 2; ++mt) ACC[mt] = MFMA(ah[mt][0], F[4], ACC[mt]); \
      _Pragma("unroll")                                                       \
      for (int mt = 0; mt < 2; ++mt) ACC[mt] = MFMA(ah[mt][1], F[5], ACC[mt]); \
      _Pragma("unroll")                                                       \
      for (int mt = 0; mt < 2; ++mt) ACC[mt] = MFMA(am[mt][0], F[0], ACC[mt]); \
      _Pragma("unroll")                                                       \
      for (int mt = 0; mt < 2; ++mt) ACC[mt] = MFMA(am[mt][1], F[1], ACC[mt]); \
      _Pragma("unroll")                                                       \
      for (int mt = 0; mt < 2; ++mt) ACC[mt] = MFMA(ah[mt][0], F[2], ACC[mt]); \
      _Pragma("unroll")                                                       \
      for (int mt = 0; mt < 2; ++mt) ACC[mt] = MFMA(ah[mt][1], F[3], ACC[mt]); \
      _Pragma("unroll")                                                       \
      for (int mt = 0; mt < 2; ++mt) ACC[mt] = MFMA(ah[mt][0], F[0], ACC[mt]); \
      _Pragma("unroll")                                                       \
      for (int mt = 0; mt < 2; ++mt) ACC[mt] = MFMA(ah[mt][1], F[1], ACC[mt]); }

// distances + running argmin (k ascending: strict < keeps lowest k)
#define TAIL(ACC, EQ, KV)                                                     \
    { _Pragma("unroll")                                                       \
      for (int mt = 0; mt < 2; ++mt)                                          \
          _Pragma("unroll")                                                   \
          for (int r2 = 0; r2 < 4; ++r2) {                                    \
              float d = fmaf(-2.f, ACC[mt][r2], (EQ));                        \
              int idx = mt * 4 + r2;                                          \
              if (d < bestd[idx]) { bestd[idx] = d; bestk[idx] = (KV); }      \
          } }

// ---- prep: split emb into B-fragment layout + pre-summed |e|^2 ----
__global__ void vq_prep(const float* __restrict__ emb,
                        unsigned short* __restrict__ bs,
                        float* __restrict__ esq) {
    const int t    = blockIdx.x * blockDim.x + threadIdx.x;  // 0..1023
    const int k    = t >> 1;
    const int half = t & 1;
    const int n16  = k & 15;
    const float* eg = emb + (size_t)k * CD + half * 32;
    unsigned short* bb = bs + (size_t)(k >> 4) * KT_USH + half * 512 + n16 * 8;
    float s = 0.f;
    #pragma unroll
    for (int q = 0; q < 8; ++q) {
        float4 ev = *(const float4*)(eg + q * 4);
        float vv[4] = {ev.x, ev.y, ev.z, ev.w};
        #pragma unroll
        for (int i = 0; i < 4; ++i) {
            s = fmaf(vv[i], vv[i], s);
            unsigned short h, m, l;
            split3(vv[i], h, m, l);
            const int c    = half * 32 + q * 4 + i;   // 0..63
            const int quad = (c >> 3) & 3;
            const int j    = c & 7;
            const int off  = quad * 128 + j;          // (quad*16)*8 + j
            bb[off]        = h;                       // lvl 0 (frag lvl*2+ch)
            bb[1024 + off] = m;                       // lvl 1
            bb[2048 + off] = l;                       // lvl 2
        }
    }
    float o = __shfl_xor(s, 1, 64);
    if (half == 0) esq[k] = s + o;    // == R7's esq_p[2k] + esq_p[2k+1]
}

// ---- main kernel: 4-slot LDS ring, frag prefetch, deferred argmin ----
__launch_bounds__(256, 4)
__global__ void vq_mfma_kernel(const float* __restrict__ x,
                               const unsigned short* __restrict__ bs,
                               const float* __restrict__ esq,
                               const float* __restrict__ emb,
                               float* __restrict__ out) {
    const int tid  = threadIdx.x;
    const int lane = tid & 63;
    const int wv   = __builtin_amdgcn_readfirstlane(tid >> 6);  // 0..3
    const int n16  = lane & 15;   // m for A, n for B, col for D
    const int quad = lane >> 4;   // k-quad for A/B, row-quad for D

    const int g0 = blockIdx.x << 7;   // 128 positions per block
    const int b  = g0 >> 12;          // 128 | 4096: no b straddle
    const int n0 = g0 & 4095;

    __shared__ unsigned short lds_b[4][KT_USH];   // 4 slots x 6144 B (ring)
    __shared__ int bk_s[PT];

    const char* bsb = (const char*)bs;
    char* lds0 = (char*)&lds_b[0][0];

    // staging split: wave wv covers chunk indices {wv, wv+4, wv+8} of the
    // 12 chunks (2 tiles x 6 frags x 1024 B) staged per round
    int st_t[3], st_c[3];
    #pragma unroll
    for (int s = 0; s < 3; ++s) {
        int cidx = wv + 4 * s;          // 0..11
        st_t[s] = (cidx < 6) ? 0 : 1;   // tile offset within the pair
        st_c[s] = (cidx < 6) ? cidx : cidx - 6;
    }

    // ---- stage tiles 0,1 first; DMA latency hides under split3 ----
    #pragma unroll
    for (int s = 0; s < 3; ++s)
        gload_lds16(bsb + (size_t)st_t[s] * TILE_B + st_c[s] * 1024 + lane * 16,
                    lds0 + st_t[s] * TILE_B + st_c[s] * 1024);

    // ---- A fragments: load x, split to 3 bf16 frags (held whole kernel) ----
    // pos = g0 + wv*32 + mt*16 + n16 ; k(c) = ch*32 + quad*8 + j
    short8 ah[2][2], am[2][2], al[2][2];
    {
        const float* xb = x + (size_t)b * (CD * HWD) + n0 + wv * 32 + n16;
        #pragma unroll
        for (int mt = 0; mt < 2; ++mt)
            #pragma unroll
            for (int ch = 0; ch < 2; ++ch) {
                #pragma unroll
                for (int j = 0; j < 8; ++j) {
                    float v = xb[(size_t)(ch * 32 + quad * 8 + j) * HWD + mt * 16];
                    unsigned short h, m, l;
                    split3(v, h, m, l);
                    ah[mt][ch][j] = (short)h;
                    am[mt][ch][j] = (short)m;
                    al[mt][ch][j] = (short)l;
                }
            }
    }

    float bestd[8]; int bestk[8];
    #pragma unroll
    for (int i = 0; i < 8; ++i) { bestd[i] = FLT_MAX; bestk[i] = 0; }

    __syncthreads();   // tiles 0,1 resident

    short8 f[6], g[6];
    floatx4 accA[2], accB[2];
    float eqBprev = 0.f;

    // ---- main loop: 16 rounds x 2 tiles; ring slot = tile & 3 ----
    #pragma unroll 1
    for (int r = 0; r < 16; ++r) {
        const int tA = 2 * r, tB = 2 * r + 1;

        // (a) f <- frags(tile tA) from slot tA&3 (staged round r-1)
        {
            const char* sb = lds0 + (tA & 3) * TILE_B;
            #pragma unroll
            for (int i = 0; i < 6; ++i)
                f[i] = *(const short8*)(sb + i * 1024 + lane * 16);
        }
        // (b) stage tiles tA+2, tB+2 into the slots read last round
        if (r < 15) {
            #pragma unroll
            for (int s = 0; s < 3; ++s) {
                const int tt = tA + 2 + st_t[s];
                gload_lds16(bsb + (size_t)tt * TILE_B + st_c[s] * 1024 + lane * 16,
                            lds0 + (tt & 3) * TILE_B + st_c[s] * 1024);
            }
        }
        const float eqa = esq[tA * 16 + n16];
        const float eqb = esq[tB * 16 + n16];
        // (c) g <- frags(tile tB) from slot tB&3 (staged round r-1)
        {
            const char* sb = lds0 + (tB & 3) * TILE_B;
            #pragma unroll
            for (int i = 0; i < 6; ++i)
                g[i] = *(const short8*)(sb + i * 1024 + lane * 16);
        }
        // (d) MFMA on f -> accA
        #pragma unroll
        for (int mt = 0; mt < 2; ++mt) accA[mt] = (floatx4){0.f, 0.f, 0.f, 0.f};
        CLUSTER(f, accA)
        // (e) deferred argmin for tile 2r-1 (acc done since last round)
        if (r > 0) TAIL(accB, eqBprev, (tA - 1) * 16 + n16)
        // (f) MFMA on g -> accB
        #pragma unroll
        for (int mt = 0; mt < 2; ++mt) accB[mt] = (floatx4){0.f, 0.f, 0.f, 0.f};
        CLUSTER(g, accB)
        // (g) argmin for tile tA (its chain drained under (e)+(f))
        TAIL(accA, eqa, tA * 16 + n16)
        eqBprev = eqb;
        // (h) barrier: drains this round's DMA (covered by ~930cy of MFMA);
        //     protects next round's slot overwrite
        __syncthreads();
    }
    // final deferred argmin: tile 31
    TAIL(accB, eqBprev, 31 * 16 + n16)

    // ---- cross-lane argmin over the 16 code-columns (lane bits 0..3) ----
    #pragma unroll
    for (int msk = 1; msk <= 8; msk <<= 1)
        #pragma unroll
        for (int i = 0; i < 8; ++i) {
            float od = __shfl_xor(bestd[i], msk, 64);
            int   ok = __shfl_xor(bestk[i], msk, 64);
            bool take = (od < bestd[i]) || (od == bestd[i] && ok < bestk[i]);
            if (take) { bestd[i] = od; bestk[i] = ok; }
        }
    // D row = quad*4 + r within tile -> pos = wv*32 + mt*16 + quad*4 + r
    if (n16 == 0) {
        #pragma unroll
        for (int mt = 0; mt < 2; ++mt)
            #pragma unroll
            for (int r = 0; r < 4; ++r)
                bk_s[wv * 32 + mt * 16 + quad * 4 + r] = bestk[mt * 4 + r];
    }
    __syncthreads();

    // ---- gather epilogue: wave-uniform rows, 256-B coalesced, batched ----
    const size_t ob = (size_t)g0 * CD;
    for (int it = 0; it < 8; ++it) {
        float v[4]; int pp[4];
        #pragma unroll
        for (int j = 0; j < 4; ++j) {
            int p = (it * 4 + j) * 4 + wv;
            pp[j] = p;
            v[j]  = emb[bk_s[p] * CD + lane];   // L2-hot fp32 row
        }
        #pragma unroll
        for (int j = 0; j < 4; ++j)
            out[ob + (size_t)pp[j] * CD + lane] = v[j];
    }
}

// ---- fallback (no workspace): verbatim R7 kernel, 123.7 us known-good ----
__launch_bounds__(256, 2)
__global__ void vq_mfma_fb(const float* __restrict__ x,
                           const float* __restrict__ emb,
                           float* __restrict__ out) {
    const int tid  = threadIdx.x;
    const int lane = tid & 63;
    const int wv   = __builtin_amdgcn_readfirstlane(tid >> 6);  // 0..3
    const int n16  = lane & 15;
    const int quad = lane >> 4;

    const int g0 = blockIdx.x << 8;
    const int b  = g0 >> 12;
    const int n0 = g0 & 4095;

    __shared__ unsigned short es_h[KT][ESR];
    __shared__ unsigned short es_m[KT][ESR];
    __shared__ unsigned short es_l[KT][ESR];
    __shared__ float esq_p[2 * KT];
    __shared__ int   bk_s[256];

    short8 ah[4][2], am[4][2], al[4][2];
    {
        const float* xb = x + (size_t)b * (CD * HWD) + n0 + wv * 64 + n16;
        #pragma unroll
        for (int mt = 0; mt < 4; ++mt)
            #pragma unroll
            for (int ch = 0; ch < 2; ++ch) {
                #pragma unroll
                for (int j = 0; j < 8; ++j) {
                    float v = xb[(size_t)(ch * 32 + quad * 8 + j) * HWD + mt * 16];
                    unsigned short h, m, l;
                    split3(v, h, m, l);
                    ah[mt][ch][j] = (short)h;
                    am[mt][ch][j] = (short)m;
                    al[mt][ch][j] = (short)l;
                }
            }
    }

    float bestd[16]; int bestk[16];
    #pragma unroll
    for (int i = 0; i < 16; ++i) { bestd[i] = FLT_MAX; bestk[i] = 0; }

    const int lr   = tid >> 1;
    const int half = tid & 1;

    for (int nt = 0; nt < KD / KT; ++nt) {
        __syncthreads();
        {
            const float* eg = emb + (size_t)(nt * KT + lr) * CD + half * 32;
            float s = 0.f;
            #pragma unroll
            for (int q = 0; q < 8; ++q) {
                float4 ev = *(const float4*)(eg + q * 4);
                float vv[4] = {ev.x, ev.y, ev.z, ev.w};
                ushort4 h4, m4, l4;
                unsigned short* hp = (unsigned short*)&h4;
                unsigned short* mp = (unsigned short*)&m4;
                unsigned short* lp = (unsigned short*)&l4;
                #pragma unroll
                for (int i = 0; i < 4; ++i) {
                    s = fmaf(vv[i], vv[i], s);
                    split3(vv[i], hp[i], mp[i], lp[i]);
                }
                int c0 = half * 32 + q * 4;
                *(ushort4*)&es_h[lr][c0] = h4;
                *(ushort4*)&es_m[lr][c0] = m4;
                *(ushort4*)&es_l[lr][c0] = l4;
            }
            esq_p[2 * lr + half] = s;
        }
        __syncthreads();

        #pragma unroll 2
        for (int ln = 0; ln < 8; ++ln) {
            const int krow = ln * 16 + n16;
            const unsigned short* ph = &es_h[krow][quad * 8];
            const unsigned short* pm = &es_m[krow][quad * 8];
            const unsigned short* pl = &es_l[krow][quad * 8];
            short8 bh0 = *(const short8*)ph,  bh1 = *(const short8*)(ph + 32);
            short8 bm0 = *(const short8*)pm,  bm1 = *(const short8*)(pm + 32);
            short8 bl0 = *(const short8*)pl,  bl1 = *(const short8*)(pl + 32);
            const float eq = esq_p[2 * krow] + esq_p[2 * krow + 1];
            const int   kv = nt * KT + ln * 16 + n16;

            floatx4 acc[4];
            #pragma unroll
            for (int mt = 0; mt < 4; ++mt) acc[mt] = (floatx4){0.f, 0.f, 0.f, 0.f};

            #define STEPF(AR, B0, B1)                                         \
                { _Pragma("unroll")                                           \
                  for (int mt = 0; mt < 4; ++mt) acc[mt] = MFMA(AR[mt][0], B0, acc[mt]); \
                  _Pragma("unroll")                                           \
                  for (int mt = 0; mt < 4; ++mt) acc[mt] = MFMA(AR[mt][1], B1, acc[mt]); }
            STEPF(al, bh0, bh1)
            STEPF(am, bm0, bm1)
            STEPF(ah, bl0, bl1)
            STEPF(am, bh0, bh1)
            STEPF(ah, bm0, bm1)
            STEPF(ah, bh0, bh1)
            #undef STEPF

            #pragma unroll
            for (int mt = 0; mt < 4; ++mt)
                #pragma unroll
                for (int r = 0; r < 4; ++r) {
                    float d = fmaf(-2.f, acc[mt][r], eq);
                    int idx = mt * 4 + r;
                    if (d < bestd[idx]) { bestd[idx] = d; bestk[idx] = kv; }
                }
        }
    }

    #pragma unroll
    for (int msk = 1; msk <= 8; msk <<= 1)
        #pragma unroll
        for (int i = 0; i < 16; ++i) {
            float od = __shfl_xor(bestd[i], msk, 64);
            int   ok = __shfl_xor(bestk[i], msk, 64);
            bool take = (od < bestd[i]) || (od == bestd[i] && ok < bestk[i]);
            if (take) { bestd[i] = od; bestk[i] = ok; }
        }
    if (n16 == 0) {
        #pragma unroll
        for (int mt = 0; mt < 4; ++mt)
            #pragma unroll
            for (int r = 0; r < 4; ++r)
                bk_s[wv * 64 + mt * 16 + quad * 4 + r] = bestk[mt * 4 + r];
    }
    __syncthreads();

    const size_t ob = (size_t)g0 * CD;
    for (int it = 0; it < 16; ++it) {
        float v[4]; int pp[4];
        #pragma unroll
        for (int j = 0; j < 4; ++j) {
            int p = (it * 4 + j) * 4 + wv;
            pp[j] = p;
            v[j]  = emb[bk_s[p] * CD + lane];
        }
        #pragma unroll
        for (int j = 0; j < 4; ++j)
            out[ob + (size_t)pp[j] * CD + lane] = v[j];
    }
}

extern "C" void kernel_launch(void* const* d_in, const int* in_sizes, int n_in,
                              void* d_out, int out_size, void* d_ws, size_t ws_size,
                              hipStream_t stream) {
    const float* x   = (const float*)d_in[0];   // 32*64*64*64
    const float* emb = (const float*)d_in[1];   // 512*64
    float* out = (float*)d_out;                 // 8388608 floats

    if (d_ws != nullptr && ws_size >= (size_t)WS_NEEDED) {
        unsigned short* bs = (unsigned short*)d_ws;     // 196608 B
        float* esq = (float*)((char*)d_ws + ESQ_OFF);   // 512 floats
        vq_prep<<<16, 64, 0, stream>>>(emb, bs, esq);
        vq_mfma_kernel<<<1024, 256, 0, stream>>>(x, bs, esq, emb, out);
    } else {
        vq_mfma_fb<<<512, 256, 0, stream>>>(x, emb, out);
    }
}